// Round 1
// baseline (794.712 us; speedup 1.0000x reference)
//
#include <hip/hip_runtime.h>
#include <hip/hip_bf16.h>

// Problem constants (from reference setup_inputs)
#define BB 4
#define NN 10000
#define CIN 512
#define H1 256
#define H2 128
#define TT 64
#define KK 10

struct Perm { int p[9]; };

// ---------------- host: exact numpy RandomState(0).permutation(19)[:9] ----------------
static void numpy_perm19(int* perm_out) {
    unsigned int mt[624];
    int mti;
    mt[0] = 0u;
    for (mti = 1; mti < 624; ++mti)
        mt[mti] = (unsigned int)(1812433253u * (mt[mti - 1] ^ (mt[mti - 1] >> 30)) + (unsigned int)mti);
    mti = 624;
    auto genrand = [&]() -> unsigned int {
        if (mti >= 624) {
            for (int kk = 0; kk < 624; ++kk) {
                unsigned int y = (mt[kk] & 0x80000000u) | (mt[(kk + 1) % 624] & 0x7fffffffu);
                mt[kk] = mt[(kk + 397) % 624] ^ (y >> 1) ^ ((y & 1u) ? 2567483615u : 0u);
            }
            mti = 0;
        }
        unsigned int y = mt[mti++];
        y ^= y >> 11;
        y ^= (y << 7) & 2636928640u;
        y ^= (y << 15) & 4022730752u;
        y ^= y >> 18;
        return y;
    };
    auto rk_interval = [&](unsigned int mx) -> unsigned int {
        if (mx == 0) return 0;
        unsigned int mask = mx;
        mask |= mask >> 1; mask |= mask >> 2; mask |= mask >> 4;
        mask |= mask >> 8; mask |= mask >> 16;
        unsigned int value;
        while ((value = (genrand() & mask)) > mx) {}
        return value;
    };
    int arr[19];
    for (int i = 0; i < 19; ++i) arr[i] = i;
    for (int i = 18; i >= 1; --i) {
        unsigned int j = rk_interval((unsigned int)i);
        int t = arr[j]; arr[j] = arr[i]; arr[i] = t;
    }
    for (int i = 0; i < 9; ++i) perm_out[i] = arr[i];
}

// ---------------- GEMM: C[M,Nc] = A[M,K] @ W[K,Nc]  (f32, 64x64 tile, 4x4 micro) ----------------
__global__ __launch_bounds__(256) void gemm_tile(const float* __restrict__ A,
                                                 const float* __restrict__ W,
                                                 float* __restrict__ C,
                                                 int M, int K, int Nc) {
    const int bx = blockIdx.x;   // col block
    const int by = blockIdx.y;   // row block
    const int tid = threadIdx.x;
    const int tx = tid & 15, ty = tid >> 4;
    __shared__ float As[32][72];   // transposed A tile: As[k][row], 288B rows (16B-aligned)
    __shared__ float Bs[32][72];   // Bs[k][col]
    const int r0 = by * 64, c0 = bx * 64;
    float acc[4][4] = {};
    for (int k0 = 0; k0 < K; k0 += 32) {
#pragma unroll
        for (int i = 0; i < 2; ++i) {
            int idx = tid + i * 256;
            int row = idx >> 3, col4 = idx & 7;
            const float4 a = *(const float4*)&A[(long)(r0 + row) * K + k0 + col4 * 4];
            As[col4 * 4 + 0][row] = a.x;
            As[col4 * 4 + 1][row] = a.y;
            As[col4 * 4 + 2][row] = a.z;
            As[col4 * 4 + 3][row] = a.w;
        }
#pragma unroll
        for (int i = 0; i < 2; ++i) {
            int idx = tid + i * 256;
            int row = idx >> 4, col4 = idx & 15;
            *(float4*)&Bs[row][col4 * 4] = *(const float4*)&W[(long)(k0 + row) * Nc + c0 + col4 * 4];
        }
        __syncthreads();
#pragma unroll
        for (int kk = 0; kk < 32; ++kk) {
            float4 a4 = *(const float4*)&As[kk][ty * 4];
            float4 b4 = *(const float4*)&Bs[kk][tx * 4];
            float av[4] = {a4.x, a4.y, a4.z, a4.w};
            float bv[4] = {b4.x, b4.y, b4.z, b4.w};
#pragma unroll
            for (int i = 0; i < 4; ++i)
#pragma unroll
                for (int j = 0; j < 4; ++j)
                    acc[i][j] += av[i] * bv[j];
        }
        __syncthreads();
    }
#pragma unroll
    for (int i = 0; i < 4; ++i) {
        float4 o = make_float4(acc[i][0], acc[i][1], acc[i][2], acc[i][3]);
        *(float4*)&C[(long)(r0 + ty * 4 + i) * Nc + c0 + tx * 4] = o;
    }
}

// ---------------- dv counts ----------------
__global__ void count_dv(const int* __restrict__ nn, Perm perm, int* __restrict__ dv, int N) {
    int idx = blockIdx.x * blockDim.x + threadIdx.x;   // over B*N
    if (idx >= BB * N) return;
    int b = idx / N;
    atomicAdd(&dv[idx], 1);   // self
    const int* row = nn + (long)idx * (2 * KK - 1);
#pragma unroll
    for (int j = 0; j < KK - 1; ++j)
        atomicAdd(&dv[b * N + row[perm.p[j]]], 1);
}

// ---------------- fused ef gather + scatter (one block per edge) ----------------
template <int H>
__global__ void edge_scatter(const float* __restrict__ y,    // [B][N][H]
                             const int* __restrict__ nn,     // [B][N][19]
                             Perm perm,
                             float* __restrict__ acc,        // [B][N][H], zeroed
                             int N) {
    const int eg = blockIdx.x;            // b*N + e
    const int b = eg / N, e = eg - b * N;
    const int c = threadIdx.x;            // H threads
    __shared__ int idx[KK];
    if (threadIdx.x < KK) {
        idx[threadIdx.x] = (threadIdx.x == 0) ? e : nn[(long)eg * (2 * KK - 1) + perm.p[threadIdx.x - 1]];
    }
    __syncthreads();
    const float* yb = y + (long)b * N * H;
    float s = 0.f;
#pragma unroll
    for (int i = 0; i < KK; ++i) s += yb[(long)idx[i] * H + c];
    s *= 0.1f;   // /de, de == 10 always
    float* ab = acc + (long)b * N * H;
#pragma unroll
    for (int i = 0; i < KK; ++i) atomicAdd(&ab[(long)idx[i] * H + c], s);
}

// ---------------- finalize: /dv + bias + leaky_relu ----------------
template <int H>
__global__ void finalize_k(const float* __restrict__ acc, const int* __restrict__ dv,
                           const float* __restrict__ bias, float* __restrict__ out,
                           long total /* B*N*H */) {
    long i = (long)blockIdx.x * blockDim.x + threadIdx.x;
    if (i >= total) return;
    long r = i / H;
    int c = (int)(i - r * H);
    int d = dv[r];
    float v = acc[i] / (float)(d > 1 ? d : 1) + bias[c];
    out[i] = v >= 0.f ? v : 0.01f * v;
}

// ---------------- mean over nodes (partial sums + atomics) ----------------
__global__ void mean_partial(const float* __restrict__ h2, float* __restrict__ meanbuf, int N) {
    const int CH = 50;                    // chunks per batch; N=10000 -> 200 rows/chunk
    int b = blockIdx.x / CH;
    int chunk = blockIdx.x % CH;
    int c = threadIdx.x;                  // 128
    int rows = N / CH;
    const float* base = h2 + ((long)b * N + (long)chunk * rows) * H2;
    float s = 0.f;
    for (int r = 0; r < rows; ++r) s += base[(long)r * H2 + c];
    atomicAdd(&meanbuf[b * H2 + c], s);
}

// ---------------- final FC: out[b][t] = (mean/N) @ fc_w + fc_b ----------------
__global__ void fc_k(const float* __restrict__ meanbuf, const float* __restrict__ fcw,
                     const float* __restrict__ fcb, float* __restrict__ out, float invN) {
    int tid = threadIdx.x;   // 256
    int b = tid / TT, t = tid % TT;
    float s = 0.f;
    for (int c = 0; c < H2; ++c) s += meanbuf[b * H2 + c] * fcw[c * TT + t];
    out[tid] = s * invN + fcb[t];
}

extern "C" void kernel_launch(void* const* d_in, const int* in_sizes, int n_in,
                              void* d_out, int out_size, void* d_ws, size_t ws_size,
                              hipStream_t stream) {
    const float* x      = (const float*)d_in[0];
    const int*   nn     = (const int*)d_in[1];
    const float* theta0 = (const float*)d_in[2];
    const float* b0     = (const float*)d_in[3];
    const float* theta1 = (const float*)d_in[4];
    const float* b1     = (const float*)d_in[5];
    const float* fcw    = (const float*)d_in[6];
    const float* fcb    = (const float*)d_in[7];
    float* out = (float*)d_out;

    Perm perm;
    numpy_perm19(perm.p);

    const long M = (long)BB * NN;                 // 40000
    float* bufA = (float*)d_ws;                   // M*H1 floats (40.96 MB)
    float* bufB = bufA + M * H1;                  // M*H1 floats
    int*   dv   = (int*)(bufB + M * H1);          // M ints
    float* meanbuf = (float*)(dv + M);            // B*H2 floats

    // --- dv counts (shared by both layers) ---
    hipMemsetAsync(dv, 0, M * sizeof(int), stream);
    count_dv<<<(M + 255) / 256, 256, 0, stream>>>(nn, perm, dv, NN);

    // --- layer 1 ---
    // y0 = x @ theta0 -> bufA [M, 256]
    gemm_tile<<<dim3(H1 / 64, M / 64), 256, 0, stream>>>(x, theta0, bufA, (int)M, CIN, H1);
    hipMemsetAsync(bufB, 0, M * H1 * sizeof(float), stream);
    edge_scatter<H1><<<(int)M, H1, 0, stream>>>(bufA, nn, perm, bufB, NN);
    finalize_k<H1><<<(int)((M * H1 + 255) / 256), 256, 0, stream>>>(bufB, dv, b0, bufA, M * H1);
    // h1 now in bufA [M, 256]

    // --- layer 2 ---
    // y1 = h1 @ theta1 -> bufB [M, 128]
    gemm_tile<<<dim3(H2 / 64, M / 64), 256, 0, stream>>>(bufA, theta1, bufB, (int)M, H1, H2);
    hipMemsetAsync(bufA, 0, M * H2 * sizeof(float), stream);
    edge_scatter<H2><<<(int)M, H2, 0, stream>>>(bufB, nn, perm, bufA, NN);
    finalize_k<H2><<<(int)((M * H2 + 255) / 256), 256, 0, stream>>>(bufA, dv, b1, bufB, M * H2);
    // h2 now in bufB [M, 128]

    // --- mean over nodes + FC ---
    hipMemsetAsync(meanbuf, 0, BB * H2 * sizeof(float), stream);
    mean_partial<<<BB * 50, H2, 0, stream>>>(bufB, meanbuf, NN);
    fc_k<<<1, BB * TT, 0, stream>>>(meanbuf, fcw, fcb, out, 1.0f / (float)NN);
}

// Round 2
// 540.240 us; speedup vs baseline: 1.4710x; 1.4710x over previous
//
#include <hip/hip_runtime.h>
#include <hip/hip_bf16.h>

// Problem constants (from reference setup_inputs)
#define BB 4
#define NN 10000
#define CIN 512
#define H1 256
#define H2 128
#define TT 64
#define KK 10

struct Perm { int p[9]; };

// ---------------- host: exact numpy RandomState(0).permutation(19)[:9] ----------------
static void numpy_perm19(int* perm_out) {
    unsigned int mt[624];
    int mti;
    mt[0] = 0u;
    for (mti = 1; mti < 624; ++mti)
        mt[mti] = (unsigned int)(1812433253u * (mt[mti - 1] ^ (mt[mti - 1] >> 30)) + (unsigned int)mti);
    mti = 624;
    auto genrand = [&]() -> unsigned int {
        if (mti >= 624) {
            for (int kk = 0; kk < 624; ++kk) {
                unsigned int y = (mt[kk] & 0x80000000u) | (mt[(kk + 1) % 624] & 0x7fffffffu);
                mt[kk] = mt[(kk + 397) % 624] ^ (y >> 1) ^ ((y & 1u) ? 2567483615u : 0u);
            }
            mti = 0;
        }
        unsigned int y = mt[mti++];
        y ^= y >> 11;
        y ^= (y << 7) & 2636928640u;
        y ^= (y << 15) & 4022730752u;
        y ^= y >> 18;
        return y;
    };
    auto rk_interval = [&](unsigned int mx) -> unsigned int {
        if (mx == 0) return 0;
        unsigned int mask = mx;
        mask |= mask >> 1; mask |= mask >> 2; mask |= mask >> 4;
        mask |= mask >> 8; mask |= mask >> 16;
        unsigned int value;
        while ((value = (genrand() & mask)) > mx) {}
        return value;
    };
    int arr[19];
    for (int i = 0; i < 19; ++i) arr[i] = i;
    for (int i = 18; i >= 1; --i) {
        unsigned int j = rk_interval((unsigned int)i);
        int t = arr[j]; arr[j] = arr[i]; arr[i] = t;
    }
    for (int i = 0; i < 9; ++i) perm_out[i] = arr[i];
}

// ---------------- GEMM: C[M,Nc] = A[M,K] @ W[K,Nc]  (f32, 64x64 tile, 4x4 micro) ----------------
__global__ __launch_bounds__(256) void gemm_tile(const float* __restrict__ A,
                                                 const float* __restrict__ W,
                                                 float* __restrict__ C,
                                                 int M, int K, int Nc) {
    const int bx = blockIdx.x;   // col block
    const int by = blockIdx.y;   // row block
    const int tid = threadIdx.x;
    const int tx = tid & 15, ty = tid >> 4;
    __shared__ float As[32][72];   // transposed A tile: As[k][row]
    __shared__ float Bs[32][72];   // Bs[k][col]
    const int r0 = by * 64, c0 = bx * 64;
    float acc[4][4] = {};
    for (int k0 = 0; k0 < K; k0 += 32) {
#pragma unroll
        for (int i = 0; i < 2; ++i) {
            int idx = tid + i * 256;
            int row = idx >> 3, col4 = idx & 7;
            const float4 a = *(const float4*)&A[(long)(r0 + row) * K + k0 + col4 * 4];
            As[col4 * 4 + 0][row] = a.x;
            As[col4 * 4 + 1][row] = a.y;
            As[col4 * 4 + 2][row] = a.z;
            As[col4 * 4 + 3][row] = a.w;
        }
#pragma unroll
        for (int i = 0; i < 2; ++i) {
            int idx = tid + i * 256;
            int row = idx >> 4, col4 = idx & 15;
            *(float4*)&Bs[row][col4 * 4] = *(const float4*)&W[(long)(k0 + row) * Nc + c0 + col4 * 4];
        }
        __syncthreads();
#pragma unroll
        for (int kk = 0; kk < 32; ++kk) {
            float4 a4 = *(const float4*)&As[kk][ty * 4];
            float4 b4 = *(const float4*)&Bs[kk][tx * 4];
            float av[4] = {a4.x, a4.y, a4.z, a4.w};
            float bv[4] = {b4.x, b4.y, b4.z, b4.w};
#pragma unroll
            for (int i = 0; i < 4; ++i)
#pragma unroll
                for (int j = 0; j < 4; ++j)
                    acc[i][j] += av[i] * bv[j];
        }
        __syncthreads();
    }
#pragma unroll
    for (int i = 0; i < 4; ++i) {
        float4 o = make_float4(acc[i][0], acc[i][1], acc[i][2], acc[i][3]);
        *(float4*)&C[(long)(r0 + ty * 4 + i) * Nc + c0 + tx * 4] = o;
    }
}

// ---------------- dv counts ----------------
__global__ void count_dv(const int* __restrict__ nn, Perm perm, int* __restrict__ dv, int N) {
    int idx = blockIdx.x * blockDim.x + threadIdx.x;   // over B*N
    if (idx >= BB * N) return;
    int b = idx / N;
    atomicAdd(&dv[idx], 1);   // self
    const int* row = nn + (long)idx * (2 * KK - 1);
#pragma unroll
    for (int j = 0; j < KK - 1; ++j)
        atomicAdd(&dv[b * N + row[perm.p[j]]], 1);
}

// ---------------- exclusive scan of dv -> offsets (single block) ----------------
__global__ __launch_bounds__(1024) void scan_offsets(const int* __restrict__ dv,
                                                     int* __restrict__ offsets, int M) {
    __shared__ int tmp[1024];
    __shared__ int carry;
    if (threadIdx.x == 0) carry = 0;
    __syncthreads();
    for (int base = 0; base < M; base += 1024) {
        int i = base + threadIdx.x;
        int v = (i < M) ? dv[i] : 0;
        tmp[threadIdx.x] = v;
        __syncthreads();
        for (int off = 1; off < 1024; off <<= 1) {
            int t = (threadIdx.x >= off) ? tmp[threadIdx.x - off] : 0;
            __syncthreads();
            tmp[threadIdx.x] += t;
            __syncthreads();
        }
        if (i < M) offsets[i] = carry + tmp[threadIdx.x] - v;
        __syncthreads();
        if (threadIdx.x == 0) carry += tmp[1023];
        __syncthreads();
    }
    if (threadIdx.x == 0) offsets[M] = carry;
}

// ---------------- fill inverse-CSR entries ----------------
__global__ void fill_entries(const int* __restrict__ nn, Perm perm,
                             const int* __restrict__ offsets, int* __restrict__ cursor,
                             int* __restrict__ entries, int N) {
    int j = blockIdx.x * blockDim.x + threadIdx.x;   // over B*N*K
    if (j >= BB * N * KK) return;
    int eg = j / KK, slot = j - eg * KK;
    int b = eg / N, e = eg - b * N;
    int node = (slot == 0) ? e : nn[(long)eg * (2 * KK - 1) + perm.p[slot - 1]];
    int g = b * N + node;
    int pos = atomicAdd(&cursor[g], 1);
    entries[offsets[g] + pos] = eg;
}

// ---------------- ef[e] = 0.1 * sum of 10 rows of y (coalesced write) ----------------
template <int H>
__global__ void edge_ef(const float* __restrict__ y, const int* __restrict__ nn, Perm perm,
                        float* __restrict__ ef, int N) {
    const int eg = blockIdx.x;            // b*N + e
    const int b = eg / N, e = eg - b * N;
    const int c = threadIdx.x;            // H threads
    __shared__ int idx[KK];
    if (threadIdx.x < KK)
        idx[threadIdx.x] = (threadIdx.x == 0) ? e : nn[(long)eg * (2 * KK - 1) + perm.p[threadIdx.x - 1]];
    __syncthreads();
    const float* yb = y + (long)b * N * H;
    float s = 0.f;
#pragma unroll
    for (int i = 0; i < KK; ++i) s += yb[(long)idx[i] * H + c];
    ef[(long)eg * H + c] = 0.1f * s;
}

// ---------------- out[v] = (sum ef over v's edge list)/dv + bias, leaky_relu ----------------
template <int H>
__global__ void node_gather(const float* __restrict__ ef, const int* __restrict__ offsets,
                            const int* __restrict__ entries, const float* __restrict__ bias,
                            float* __restrict__ out) {
    const int g = blockIdx.x;             // b*N + v
    const int c = threadIdx.x;            // H threads
    const int s0 = offsets[g], s1 = offsets[g + 1];
    const int cnt = s1 - s0;              // == dv[g], >= 1 (self)
    __shared__ int eidx[64];
    float s = 0.f;
    for (int base = s0; base < s1; base += 64) {
        int m = min(64, s1 - base);
        if (threadIdx.x < m) eidx[threadIdx.x] = entries[base + threadIdx.x];
        __syncthreads();
        for (int i = 0; i < m; ++i) s += ef[(long)eidx[i] * H + c];
        __syncthreads();
    }
    float v = s / (float)cnt + bias[c];
    out[(long)g * H + c] = v >= 0.f ? v : 0.01f * v;
}

// ---------------- mean over nodes (partial sums + atomics) ----------------
__global__ void mean_partial(const float* __restrict__ h2, float* __restrict__ meanbuf, int N) {
    const int CH = 50;
    int b = blockIdx.x / CH;
    int chunk = blockIdx.x % CH;
    int c = threadIdx.x;                  // 128
    int rows = N / CH;
    const float* base = h2 + ((long)b * N + (long)chunk * rows) * H2;
    float s = 0.f;
    for (int r = 0; r < rows; ++r) s += base[(long)r * H2 + c];
    atomicAdd(&meanbuf[b * H2 + c], s);
}

// ---------------- final FC ----------------
__global__ void fc_k(const float* __restrict__ meanbuf, const float* __restrict__ fcw,
                     const float* __restrict__ fcb, float* __restrict__ out, float invN) {
    int tid = threadIdx.x;   // 256
    int b = tid / TT, t = tid % TT;
    float s = 0.f;
    for (int c = 0; c < H2; ++c) s += meanbuf[b * H2 + c] * fcw[c * TT + t];
    out[tid] = s * invN + fcb[t];
}

extern "C" void kernel_launch(void* const* d_in, const int* in_sizes, int n_in,
                              void* d_out, int out_size, void* d_ws, size_t ws_size,
                              hipStream_t stream) {
    const float* x      = (const float*)d_in[0];
    const int*   nn     = (const int*)d_in[1];
    const float* theta0 = (const float*)d_in[2];
    const float* b0     = (const float*)d_in[3];
    const float* theta1 = (const float*)d_in[4];
    const float* b1     = (const float*)d_in[5];
    const float* fcw    = (const float*)d_in[6];
    const float* fcb    = (const float*)d_in[7];
    float* out = (float*)d_out;

    Perm perm;
    numpy_perm19(perm.p);

    const long M = (long)BB * NN;                 // 40000
    const int  E = BB * NN * KK;                  // 400000 entries
    float* bufA = (float*)d_ws;                   // M*H1 floats (40.96 MB)
    float* bufB = bufA + M * H1;                  // M*H1 floats
    int*   dv      = (int*)(bufB + M * H1);       // M
    int*   offsets = dv + M;                      // M+1
    int*   cursor  = offsets + M + 1;             // M
    int*   entries = cursor + M;                  // E
    float* meanbuf = (float*)(entries + E);       // B*H2

    // --- inverse-CSR build (depends only on nn_idx) ---
    hipMemsetAsync(dv, 0, M * sizeof(int), stream);
    hipMemsetAsync(cursor, 0, M * sizeof(int), stream);
    count_dv<<<(int)((M + 255) / 256), 256, 0, stream>>>(nn, perm, dv, NN);
    scan_offsets<<<1, 1024, 0, stream>>>(dv, offsets, (int)M);
    fill_entries<<<(E + 255) / 256, 256, 0, stream>>>(nn, perm, offsets, cursor, entries, NN);

    // --- layer 1 ---
    gemm_tile<<<dim3(H1 / 64, (int)(M / 64)), 256, 0, stream>>>(x, theta0, bufA, (int)M, CIN, H1);
    edge_ef<H1><<<(int)M, H1, 0, stream>>>(bufA, nn, perm, bufB, NN);
    node_gather<H1><<<(int)M, H1, 0, stream>>>(bufB, offsets, entries, b0, bufA);
    // h1 in bufA [M, 256]

    // --- layer 2 ---
    gemm_tile<<<dim3(H2 / 64, (int)(M / 64)), 256, 0, stream>>>(bufA, theta1, bufB, (int)M, H1, H2);
    edge_ef<H2><<<(int)M, H2, 0, stream>>>(bufB, nn, perm, bufA, NN);
    node_gather<H2><<<(int)M, H2, 0, stream>>>(bufA, offsets, entries, b1, bufB);
    // h2 in bufB [M, 128]

    // --- mean over nodes + FC ---
    hipMemsetAsync(meanbuf, 0, BB * H2 * sizeof(float), stream);
    mean_partial<<<BB * 50, H2, 0, stream>>>(bufB, meanbuf, NN);
    fc_k<<<1, BB * TT, 0, stream>>>(meanbuf, fcw, fcb, out, 1.0f / (float)NN);
}

// Round 3
// 429.824 us; speedup vs baseline: 1.8489x; 1.2569x over previous
//
#include <hip/hip_runtime.h>
#include <hip/hip_bf16.h>

// Problem constants (from reference setup_inputs)
#define BB 4
#define NN 10000
#define CIN 512
#define H1 256
#define H2 128
#define TT 64
#define KK 10

struct Perm { int p[9]; };

// ---------------- host: exact numpy RandomState(0).permutation(19)[:9] ----------------
static void numpy_perm19(int* perm_out) {
    unsigned int mt[624];
    int mti;
    mt[0] = 0u;
    for (mti = 1; mti < 624; ++mti)
        mt[mti] = (unsigned int)(1812433253u * (mt[mti - 1] ^ (mt[mti - 1] >> 30)) + (unsigned int)mti);
    mti = 624;
    auto genrand = [&]() -> unsigned int {
        if (mti >= 624) {
            for (int kk = 0; kk < 624; ++kk) {
                unsigned int y = (mt[kk] & 0x80000000u) | (mt[(kk + 1) % 624] & 0x7fffffffu);
                mt[kk] = mt[(kk + 397) % 624] ^ (y >> 1) ^ ((y & 1u) ? 2567483615u : 0u);
            }
            mti = 0;
        }
        unsigned int y = mt[mti++];
        y ^= y >> 11;
        y ^= (y << 7) & 2636928640u;
        y ^= (y << 15) & 4022730752u;
        y ^= y >> 18;
        return y;
    };
    auto rk_interval = [&](unsigned int mx) -> unsigned int {
        if (mx == 0) return 0;
        unsigned int mask = mx;
        mask |= mask >> 1; mask |= mask >> 2; mask |= mask >> 4;
        mask |= mask >> 8; mask |= mask >> 16;
        unsigned int value;
        while ((value = (genrand() & mask)) > mx) {}
        return value;
    };
    int arr[19];
    for (int i = 0; i < 19; ++i) arr[i] = i;
    for (int i = 18; i >= 1; --i) {
        unsigned int j = rk_interval((unsigned int)i);
        int t = arr[j]; arr[j] = arr[i]; arr[i] = t;
    }
    for (int i = 0; i < 9; ++i) perm_out[i] = arr[i];
}

// ---------------- split-bf16 helpers ----------------
typedef __attribute__((ext_vector_type(8))) short bf16x8;
typedef __attribute__((ext_vector_type(4))) float f32x4;

__device__ __forceinline__ short f2bf(float f) {
    unsigned u = __float_as_uint(f);
    u = u + 0x7FFFu + ((u >> 16) & 1u);
    return (short)(u >> 16);
}
__device__ __forceinline__ float bf2f(short s) {
    return __uint_as_float(((unsigned)(unsigned short)s) << 16);
}

// ---------------- GEMM: C[M,Nc] = A[M,K] @ W[K,Nc], split-bf16 3-term MFMA ----------------
// BM=128, BN=64, 256 threads (4 waves in 2x2), per-wave 64x32 via 4x2 16x16x32 fragments.
__global__ __launch_bounds__(256) void gemm_mfma(const float* __restrict__ A,
                                                 const float* __restrict__ W,
                                                 float* __restrict__ C,
                                                 int M, int K, int Nc) {
    __shared__ __attribute__((aligned(16))) short Ah[128][40];  // pad: 80B row stride
    __shared__ __attribute__((aligned(16))) short Al[128][40];
    __shared__ __attribute__((aligned(16))) short Bh[64][40];   // transposed: [col][k]
    __shared__ __attribute__((aligned(16))) short Bl[64][40];
    const int tid = threadIdx.x;
    const int lane = tid & 63;
    const int wid = tid >> 6;
    const int wr = wid >> 1, wc = wid & 1;
    const int r0 = blockIdx.y * 128, c0 = blockIdx.x * 64;
    const int l15 = lane & 15, lq = lane >> 4;

    f32x4 acc[4][2] = {};

    const int bc = tid & 63;                  // B: col within tile
    const int bkg = (tid >> 6) * 8;           // B: k-chunk base
    const int bxor = ((bc >> 3) & 3) << 4;    // byte-XOR spreads rows c,c+8,c+16,c+24

    for (int k0 = 0; k0 < K; k0 += 32) {
        // ---- stage A: 128x32 f32 -> hi/lo bf16 planes ----
#pragma unroll
        for (int i = 0; i < 4; ++i) {
            int idx = tid + i * 256;              // 0..1023
            int row = idx >> 3, q = idx & 7;      // q = float4 slot (k = q*4)
            int gr = r0 + row; if (gr >= M) gr = M - 1;
            const float4 a = *(const float4*)&A[(long)gr * K + k0 + q * 4];
            short4 h, l;
            h.x = f2bf(a.x); l.x = f2bf(a.x - bf2f(h.x));
            h.y = f2bf(a.y); l.y = f2bf(a.y - bf2f(h.y));
            h.z = f2bf(a.z); l.z = f2bf(a.z - bf2f(h.z));
            h.w = f2bf(a.w); l.w = f2bf(a.w - bf2f(h.w));
            *(short4*)&Ah[row][q * 4] = h;
            *(short4*)&Al[row][q * 4] = l;
        }
        // ---- stage B: 32x64 f32 -> hi/lo bf16, transposed with XOR swizzle ----
        {
            float v[8];
#pragma unroll
            for (int j = 0; j < 8; ++j)
                v[j] = W[(long)(k0 + bkg + j) * Nc + c0 + bc];
            short h[8], l[8];
#pragma unroll
            for (int j = 0; j < 8; ++j) { h[j] = f2bf(v[j]); l[j] = f2bf(v[j] - bf2f(h[j])); }
            char* ph = (char*)&Bh[0][0] + bc * 80 + ((bkg * 2) ^ bxor);
            char* pl = (char*)&Bl[0][0] + bc * 80 + ((bkg * 2) ^ bxor);
            *(bf16x8*)ph = *(const bf16x8*)&h[0];
            *(bf16x8*)pl = *(const bf16x8*)&l[0];
        }
        __syncthreads();
        // ---- fragments + MFMA (hi*hi + hi*lo + lo*hi) ----
        bf16x8 afh[4], afl[4], bfh[2], bfl[2];
#pragma unroll
        for (int m = 0; m < 4; ++m) {
            int row = wr * 64 + m * 16 + l15;
            afh[m] = *(const bf16x8*)&Ah[row][lq * 8];
            afl[m] = *(const bf16x8*)&Al[row][lq * 8];
        }
#pragma unroll
        for (int n = 0; n < 2; ++n) {
            int col = wc * 32 + n * 16 + l15;
            int xr = ((col >> 3) & 3) << 4;
            const char* ph = (const char*)&Bh[0][0] + col * 80 + ((lq * 16) ^ xr);
            const char* pl = (const char*)&Bl[0][0] + col * 80 + ((lq * 16) ^ xr);
            bfh[n] = *(const bf16x8*)ph;
            bfl[n] = *(const bf16x8*)pl;
        }
#pragma unroll
        for (int m = 0; m < 4; ++m)
#pragma unroll
            for (int n = 0; n < 2; ++n) {
                acc[m][n] = __builtin_amdgcn_mfma_f32_16x16x32_bf16(afh[m], bfh[n], acc[m][n], 0, 0, 0);
                acc[m][n] = __builtin_amdgcn_mfma_f32_16x16x32_bf16(afh[m], bfl[n], acc[m][n], 0, 0, 0);
                acc[m][n] = __builtin_amdgcn_mfma_f32_16x16x32_bf16(afl[m], bfh[n], acc[m][n], 0, 0, 0);
            }
        __syncthreads();
    }
    // ---- store (C/D: col=lane&15, row=(lane>>4)*4+reg) ----
#pragma unroll
    for (int m = 0; m < 4; ++m)
#pragma unroll
        for (int n = 0; n < 2; ++n)
#pragma unroll
            for (int j = 0; j < 4; ++j) {
                int row = r0 + wr * 64 + m * 16 + lq * 4 + j;
                int col = c0 + wc * 32 + n * 16 + l15;
                if (row < M) C[(long)row * Nc + col] = acc[m][n][j];
            }
}

// ---------------- dv counts ----------------
__global__ void count_dv(const int* __restrict__ nn, Perm perm, int* __restrict__ dv, int N) {
    int idx = blockIdx.x * blockDim.x + threadIdx.x;   // over B*N
    if (idx >= BB * N) return;
    int b = idx / N;
    atomicAdd(&dv[idx], 1);   // self
    const int* row = nn + (long)idx * (2 * KK - 1);
#pragma unroll
    for (int j = 0; j < KK - 1; ++j)
        atomicAdd(&dv[b * N + row[perm.p[j]]], 1);
}

// ---------------- exclusive scan of dv -> offsets (one pass, thread-coarsened) ----------------
__global__ __launch_bounds__(1024) void scan_offsets(const int* __restrict__ dv,
                                                     int* __restrict__ offsets, int M) {
    const int PT = (M + 1023) / 1024;   // elems per thread (40)
    const int tid = threadIdx.x;
    const int start = tid * PT;
    int s = 0;
    for (int i = 0; i < PT; ++i) { int idx = start + i; if (idx < M) s += dv[idx]; }
    __shared__ int tmp[1024];
    tmp[tid] = s;
    __syncthreads();
    for (int off = 1; off < 1024; off <<= 1) {
        int t = (tid >= off) ? tmp[tid - off] : 0;
        __syncthreads();
        tmp[tid] += t;
        __syncthreads();
    }
    int run = tmp[tid] - s;   // exclusive base
    for (int i = 0; i < PT; ++i) {
        int idx = start + i;
        if (idx < M) { offsets[idx] = run; run += dv[idx]; }
    }
    if (tid == 1023) offsets[M] = run;
}

// ---------------- fill inverse-CSR entries ----------------
__global__ void fill_entries(const int* __restrict__ nn, Perm perm,
                             const int* __restrict__ offsets, int* __restrict__ cursor,
                             int* __restrict__ entries, int N) {
    int j = blockIdx.x * blockDim.x + threadIdx.x;   // over B*N*K
    if (j >= BB * N * KK) return;
    int eg = j / KK, slot = j - eg * KK;
    int b = eg / N, e = eg - b * N;
    int node = (slot == 0) ? e : nn[(long)eg * (2 * KK - 1) + perm.p[slot - 1]];
    int g = b * N + node;
    int pos = atomicAdd(&cursor[g], 1);
    entries[offsets[g] + pos] = eg;
}

// ---------------- ef[e] = 0.1 * sum of 10 rows of y (coalesced write) ----------------
template <int H>
__global__ void edge_ef(const float* __restrict__ y, const int* __restrict__ nn, Perm perm,
                        float* __restrict__ ef, int N) {
    const int eg = blockIdx.x;            // b*N + e
    const int b = eg / N, e = eg - b * N;
    const int c = threadIdx.x;            // H threads
    __shared__ int idx[KK];
    if (threadIdx.x < KK)
        idx[threadIdx.x] = (threadIdx.x == 0) ? e : nn[(long)eg * (2 * KK - 1) + perm.p[threadIdx.x - 1]];
    __syncthreads();
    const float* yb = y + (long)b * N * H;
    float s = 0.f;
#pragma unroll
    for (int i = 0; i < KK; ++i) s += yb[(long)idx[i] * H + c];
    ef[(long)eg * H + c] = 0.1f * s;
}

// ---------------- out[v] = (sum ef over v's edge list)/dv + bias, leaky_relu ----------------
template <int H>
__global__ void node_gather(const float* __restrict__ ef, const int* __restrict__ offsets,
                            const int* __restrict__ entries, const float* __restrict__ bias,
                            float* __restrict__ out) {
    const int g = blockIdx.x;             // b*N + v
    const int c = threadIdx.x;            // H threads
    const int s0 = offsets[g], s1 = offsets[g + 1];
    const int cnt = s1 - s0;              // == dv[g], >= 1 (self)
    __shared__ int eidx[64];
    float s = 0.f;
    for (int base = s0; base < s1; base += 64) {
        int m = min(64, s1 - base);
        if (threadIdx.x < m) eidx[threadIdx.x] = entries[base + threadIdx.x];
        __syncthreads();
        for (int i = 0; i < m; ++i) s += ef[(long)eidx[i] * H + c];
        __syncthreads();
    }
    float v = s / (float)cnt + bias[c];
    out[(long)g * H + c] = v >= 0.f ? v : 0.01f * v;
}

// ---------------- mean over nodes (partial sums + atomics) ----------------
__global__ void mean_partial(const float* __restrict__ h2, float* __restrict__ meanbuf, int N) {
    const int CH = 50;
    int b = blockIdx.x / CH;
    int chunk = blockIdx.x % CH;
    int c = threadIdx.x;                  // 128
    int rows = N / CH;
    const float* base = h2 + ((long)b * N + (long)chunk * rows) * H2;
    float s = 0.f;
    for (int r = 0; r < rows; ++r) s += base[(long)r * H2 + c];
    atomicAdd(&meanbuf[b * H2 + c], s);
}

// ---------------- final FC ----------------
__global__ void fc_k(const float* __restrict__ meanbuf, const float* __restrict__ fcw,
                     const float* __restrict__ fcb, float* __restrict__ out, float invN) {
    int tid = threadIdx.x;   // 256
    int b = tid / TT, t = tid % TT;
    float s = 0.f;
    for (int c = 0; c < H2; ++c) s += meanbuf[b * H2 + c] * fcw[c * TT + t];
    out[tid] = s * invN + fcb[t];
}

extern "C" void kernel_launch(void* const* d_in, const int* in_sizes, int n_in,
                              void* d_out, int out_size, void* d_ws, size_t ws_size,
                              hipStream_t stream) {
    const float* x      = (const float*)d_in[0];
    const int*   nn     = (const int*)d_in[1];
    const float* theta0 = (const float*)d_in[2];
    const float* b0     = (const float*)d_in[3];
    const float* theta1 = (const float*)d_in[4];
    const float* b1     = (const float*)d_in[5];
    const float* fcw    = (const float*)d_in[6];
    const float* fcb    = (const float*)d_in[7];
    float* out = (float*)d_out;

    Perm perm;
    numpy_perm19(perm.p);

    const long M = (long)BB * NN;                 // 40000
    const int  E = BB * NN * KK;                  // 400000 entries
    float* bufA = (float*)d_ws;                   // M*H1 floats
    float* bufB = bufA + M * H1;                  // M*H1 floats
    int*   dv      = (int*)(bufB + M * H1);       // M
    int*   offsets = dv + M;                      // M+1
    int*   cursor  = offsets + M + 1;             // M
    int*   entries = cursor + M;                  // E
    float* meanbuf = (float*)(entries + E);       // B*H2

    // --- inverse-CSR build (depends only on nn_idx) ---
    hipMemsetAsync(dv, 0, M * sizeof(int), stream);
    hipMemsetAsync(cursor, 0, M * sizeof(int), stream);
    count_dv<<<(int)((M + 255) / 256), 256, 0, stream>>>(nn, perm, dv, NN);
    scan_offsets<<<1, 1024, 0, stream>>>(dv, offsets, (int)M);
    fill_entries<<<(E + 255) / 256, 256, 0, stream>>>(nn, perm, offsets, cursor, entries, NN);

    const int MB = (int)((M + 127) / 128);        // 313 row blocks

    // --- layer 1 ---
    gemm_mfma<<<dim3(H1 / 64, MB), 256, 0, stream>>>(x, theta0, bufA, (int)M, CIN, H1);
    edge_ef<H1><<<(int)M, H1, 0, stream>>>(bufA, nn, perm, bufB, NN);
    node_gather<H1><<<(int)M, H1, 0, stream>>>(bufB, offsets, entries, b0, bufA);
    // h1 in bufA [M, 256]

    // --- layer 2 ---
    gemm_mfma<<<dim3(H2 / 64, MB), 256, 0, stream>>>(bufA, theta1, bufB, (int)M, H1, H2);
    edge_ef<H2><<<(int)M, H2, 0, stream>>>(bufB, nn, perm, bufA, NN);
    node_gather<H2><<<(int)M, H2, 0, stream>>>(bufA, offsets, entries, b1, bufB);
    // h2 in bufB [M, 128]

    // --- mean over nodes + FC ---
    hipMemsetAsync(meanbuf, 0, BB * H2 * sizeof(float), stream);
    mean_partial<<<BB * 50, H2, 0, stream>>>(bufB, meanbuf, NN);
    fc_k<<<1, BB * TT, 0, stream>>>(meanbuf, fcw, fcb, out, 1.0f / (float)NN);
}

// Round 4
// 363.828 us; speedup vs baseline: 2.1843x; 1.1814x over previous
//
#include <hip/hip_runtime.h>
#include <hip/hip_bf16.h>

// Problem constants (from reference setup_inputs)
#define BB 4
#define NN 10000
#define CIN 512
#define H1 256
#define H2 128
#define TT 64
#define KK 10

struct Perm { int p[9]; };

// ---------------- host: exact numpy RandomState(0).permutation(19)[:9] ----------------
static void numpy_perm19(int* perm_out) {
    unsigned int mt[624];
    int mti;
    mt[0] = 0u;
    for (mti = 1; mti < 624; ++mti)
        mt[mti] = (unsigned int)(1812433253u * (mt[mti - 1] ^ (mt[mti - 1] >> 30)) + (unsigned int)mti);
    mti = 624;
    auto genrand = [&]() -> unsigned int {
        if (mti >= 624) {
            for (int kk = 0; kk < 624; ++kk) {
                unsigned int y = (mt[kk] & 0x80000000u) | (mt[(kk + 1) % 624] & 0x7fffffffu);
                mt[kk] = mt[(kk + 397) % 624] ^ (y >> 1) ^ ((y & 1u) ? 2567483615u : 0u);
            }
            mti = 0;
        }
        unsigned int y = mt[mti++];
        y ^= y >> 11;
        y ^= (y << 7) & 2636928640u;
        y ^= (y << 15) & 4022730752u;
        y ^= y >> 18;
        return y;
    };
    auto rk_interval = [&](unsigned int mx) -> unsigned int {
        if (mx == 0) return 0;
        unsigned int mask = mx;
        mask |= mask >> 1; mask |= mask >> 2; mask |= mask >> 4;
        mask |= mask >> 8; mask |= mask >> 16;
        unsigned int value;
        while ((value = (genrand() & mask)) > mx) {}
        return value;
    };
    int arr[19];
    for (int i = 0; i < 19; ++i) arr[i] = i;
    for (int i = 18; i >= 1; --i) {
        unsigned int j = rk_interval((unsigned int)i);
        int t = arr[j]; arr[j] = arr[i]; arr[i] = t;
    }
    for (int i = 0; i < 9; ++i) perm_out[i] = arr[i];
}

// ---------------- split-bf16 helpers ----------------
typedef __attribute__((ext_vector_type(8))) short bf16x8;
typedef __attribute__((ext_vector_type(4))) float f32x4;

__device__ __forceinline__ short f2bf(float f) {
    unsigned u = __float_as_uint(f);
    u = u + 0x7FFFu + ((u >> 16) & 1u);
    return (short)(u >> 16);
}
__device__ __forceinline__ float bf2f(short s) {
    return __uint_as_float(((unsigned)(unsigned short)s) << 16);
}

// ---------------- GEMM: C[M,Nc] = A[M,K] @ W[K,Nc], split-bf16 3-term MFMA ----------------
// BM=128, BN=64, 256 threads (4 waves in 2x2), per-wave 64x32 via 4x2 16x16x32 fragments.
__global__ __launch_bounds__(256) void gemm_mfma(const float* __restrict__ A,
                                                 const float* __restrict__ W,
                                                 float* __restrict__ C,
                                                 int M, int K, int Nc) {
    __shared__ __attribute__((aligned(16))) short Ah[128][40];  // pad: 80B row stride
    __shared__ __attribute__((aligned(16))) short Al[128][40];
    __shared__ __attribute__((aligned(16))) short Bh[64][40];   // transposed: [col][k]
    __shared__ __attribute__((aligned(16))) short Bl[64][40];
    const int tid = threadIdx.x;
    const int lane = tid & 63;
    const int wid = tid >> 6;
    const int wr = wid >> 1, wc = wid & 1;
    const int r0 = blockIdx.y * 128, c0 = blockIdx.x * 64;
    const int l15 = lane & 15, lq = lane >> 4;

    f32x4 acc[4][2] = {};

    const int bc = tid & 63;                  // B: col within tile
    const int bkg = (tid >> 6) * 8;           // B: k-chunk base
    const int bxor = ((bc >> 3) & 3) << 4;    // byte-XOR spreads rows c,c+8,c+16,c+24

    for (int k0 = 0; k0 < K; k0 += 32) {
        // ---- stage A: 128x32 f32 -> hi/lo bf16 planes ----
#pragma unroll
        for (int i = 0; i < 4; ++i) {
            int idx = tid + i * 256;              // 0..1023
            int row = idx >> 3, q = idx & 7;      // q = float4 slot (k = q*4)
            int gr = r0 + row; if (gr >= M) gr = M - 1;
            const float4 a = *(const float4*)&A[(long)gr * K + k0 + q * 4];
            short4 h, l;
            h.x = f2bf(a.x); l.x = f2bf(a.x - bf2f(h.x));
            h.y = f2bf(a.y); l.y = f2bf(a.y - bf2f(h.y));
            h.z = f2bf(a.z); l.z = f2bf(a.z - bf2f(h.z));
            h.w = f2bf(a.w); l.w = f2bf(a.w - bf2f(h.w));
            *(short4*)&Ah[row][q * 4] = h;
            *(short4*)&Al[row][q * 4] = l;
        }
        // ---- stage B: 32x64 f32 -> hi/lo bf16, transposed with XOR swizzle ----
        {
            float v[8];
#pragma unroll
            for (int j = 0; j < 8; ++j)
                v[j] = W[(long)(k0 + bkg + j) * Nc + c0 + bc];
            short h[8], l[8];
#pragma unroll
            for (int j = 0; j < 8; ++j) { h[j] = f2bf(v[j]); l[j] = f2bf(v[j] - bf2f(h[j])); }
            char* ph = (char*)&Bh[0][0] + bc * 80 + ((bkg * 2) ^ bxor);
            char* pl = (char*)&Bl[0][0] + bc * 80 + ((bkg * 2) ^ bxor);
            *(bf16x8*)ph = *(const bf16x8*)&h[0];
            *(bf16x8*)pl = *(const bf16x8*)&l[0];
        }
        __syncthreads();
        // ---- fragments + MFMA (hi*hi + hi*lo + lo*hi) ----
        bf16x8 afh[4], afl[4], bfh[2], bfl[2];
#pragma unroll
        for (int m = 0; m < 4; ++m) {
            int row = wr * 64 + m * 16 + l15;
            afh[m] = *(const bf16x8*)&Ah[row][lq * 8];
            afl[m] = *(const bf16x8*)&Al[row][lq * 8];
        }
#pragma unroll
        for (int n = 0; n < 2; ++n) {
            int col = wc * 32 + n * 16 + l15;
            int xr = ((col >> 3) & 3) << 4;
            const char* ph = (const char*)&Bh[0][0] + col * 80 + ((lq * 16) ^ xr);
            const char* pl = (const char*)&Bl[0][0] + col * 80 + ((lq * 16) ^ xr);
            bfh[n] = *(const bf16x8*)ph;
            bfl[n] = *(const bf16x8*)pl;
        }
#pragma unroll
        for (int m = 0; m < 4; ++m)
#pragma unroll
            for (int n = 0; n < 2; ++n) {
                acc[m][n] = __builtin_amdgcn_mfma_f32_16x16x32_bf16(afh[m], bfh[n], acc[m][n], 0, 0, 0);
                acc[m][n] = __builtin_amdgcn_mfma_f32_16x16x32_bf16(afh[m], bfl[n], acc[m][n], 0, 0, 0);
                acc[m][n] = __builtin_amdgcn_mfma_f32_16x16x32_bf16(afl[m], bfh[n], acc[m][n], 0, 0, 0);
            }
        __syncthreads();
    }
    // ---- store (C/D: col=lane&15, row=(lane>>4)*4+reg) ----
#pragma unroll
    for (int m = 0; m < 4; ++m)
#pragma unroll
        for (int n = 0; n < 2; ++n)
#pragma unroll
            for (int j = 0; j < 4; ++j) {
                int row = r0 + wr * 64 + m * 16 + lq * 4 + j;
                int col = c0 + wc * 32 + n * 16 + l15;
                if (row < M) C[(long)row * Nc + col] = acc[m][n][j];
            }
}

// ---------------- dv counts ----------------
__global__ void count_dv(const int* __restrict__ nn, Perm perm, int* __restrict__ dv, int N) {
    int idx = blockIdx.x * blockDim.x + threadIdx.x;   // over B*N
    if (idx >= BB * N) return;
    int b = idx / N;
    atomicAdd(&dv[idx], 1);   // self
    const int* row = nn + (long)idx * (2 * KK - 1);
#pragma unroll
    for (int j = 0; j < KK - 1; ++j)
        atomicAdd(&dv[b * N + row[perm.p[j]]], 1);
}

// ---------------- multi-block exclusive scan: dv -> offsets ----------------
__global__ __launch_bounds__(256) void block_sums(const int* __restrict__ dv,
                                                  int* __restrict__ bsum, int M) {
    __shared__ int tmp[256];
    int i = blockIdx.x * 256 + threadIdx.x;
    tmp[threadIdx.x] = (i < M) ? dv[i] : 0;
    __syncthreads();
#pragma unroll
    for (int off = 128; off > 0; off >>= 1) {
        if (threadIdx.x < off) tmp[threadIdx.x] += tmp[threadIdx.x + off];
        __syncthreads();
    }
    if (threadIdx.x == 0) bsum[blockIdx.x] = tmp[0];
}

__global__ __launch_bounds__(256) void scan_bsum(int* __restrict__ bsum, int nb) {
    __shared__ int tmp[256];
    int v = (threadIdx.x < nb) ? bsum[threadIdx.x] : 0;
    tmp[threadIdx.x] = v;
    __syncthreads();
#pragma unroll
    for (int off = 1; off < 256; off <<= 1) {
        int t = (threadIdx.x >= off) ? tmp[threadIdx.x - off] : 0;
        __syncthreads();
        tmp[threadIdx.x] += t;
        __syncthreads();
    }
    if (threadIdx.x < nb) bsum[threadIdx.x] = tmp[threadIdx.x] - v;   // exclusive
}

__global__ __launch_bounds__(256) void write_offsets(const int* __restrict__ dv,
                                                     const int* __restrict__ bsum,
                                                     int* __restrict__ offsets, int M) {
    __shared__ int tmp[256];
    int i = blockIdx.x * 256 + threadIdx.x;
    int v = (i < M) ? dv[i] : 0;
    tmp[threadIdx.x] = v;
    __syncthreads();
#pragma unroll
    for (int off = 1; off < 256; off <<= 1) {
        int t = (threadIdx.x >= off) ? tmp[threadIdx.x - off] : 0;
        __syncthreads();
        tmp[threadIdx.x] += t;
        __syncthreads();
    }
    if (i < M) offsets[i] = bsum[blockIdx.x] + tmp[threadIdx.x] - v;
    if (i == M - 1) offsets[M] = bsum[blockIdx.x] + tmp[threadIdx.x];
}

// ---------------- fill inverse-CSR entries ----------------
__global__ void fill_entries(const int* __restrict__ nn, Perm perm,
                             const int* __restrict__ offsets, int* __restrict__ cursor,
                             int* __restrict__ entries, int N) {
    int j = blockIdx.x * blockDim.x + threadIdx.x;   // over B*N*K
    if (j >= BB * N * KK) return;
    int eg = j / KK, slot = j - eg * KK;
    int b = eg / N, e = eg - b * N;
    int node = (slot == 0) ? e : nn[(long)eg * (2 * KK - 1) + perm.p[slot - 1]];
    int g = b * N + node;
    int pos = atomicAdd(&cursor[g], 1);
    entries[offsets[g] + pos] = eg;
}

// ---------------- ef[e] = 0.1 * sum of 10 rows of y (coalesced write) ----------------
template <int H>
__global__ void edge_ef(const float* __restrict__ y, const int* __restrict__ nn, Perm perm,
                        float* __restrict__ ef, int N) {
    const int eg = blockIdx.x;            // b*N + e
    const int b = eg / N, e = eg - b * N;
    const int c = threadIdx.x;            // H threads
    __shared__ int idx[KK];
    if (threadIdx.x < KK)
        idx[threadIdx.x] = (threadIdx.x == 0) ? e : nn[(long)eg * (2 * KK - 1) + perm.p[threadIdx.x - 1]];
    __syncthreads();
    const float* yb = y + (long)b * N * H;
    float s = 0.f;
#pragma unroll
    for (int i = 0; i < KK; ++i) s += yb[(long)idx[i] * H + c];
    ef[(long)eg * H + c] = 0.1f * s;
}

// ---------------- out[v] = (sum ef over v's edge list)/dv + bias, leaky_relu ----------------
template <int H>
__global__ void node_gather(const float* __restrict__ ef, const int* __restrict__ offsets,
                            const int* __restrict__ entries, const float* __restrict__ bias,
                            float* __restrict__ out) {
    const int g = blockIdx.x;             // b*N + v
    const int c = threadIdx.x;            // H threads
    const int s0 = offsets[g], s1 = offsets[g + 1];
    const int cnt = s1 - s0;              // == dv[g], >= 1 (self)
    __shared__ int eidx[64];
    float s = 0.f;
    for (int base = s0; base < s1; base += 64) {
        int m = min(64, s1 - base);
        if (threadIdx.x < m) eidx[threadIdx.x] = entries[base + threadIdx.x];
        __syncthreads();
        for (int i = 0; i < m; ++i) s += ef[(long)eidx[i] * H + c];
        __syncthreads();
    }
    float v = s / (float)cnt + bias[c];
    out[(long)g * H + c] = v >= 0.f ? v : 0.01f * v;
}

// ---------------- mean over nodes (partial sums + atomics) ----------------
__global__ void mean_partial(const float* __restrict__ h2, float* __restrict__ meanbuf, int N) {
    const int CH = 50;
    int b = blockIdx.x / CH;
    int chunk = blockIdx.x % CH;
    int c = threadIdx.x;                  // 128
    int rows = N / CH;
    const float* base = h2 + ((long)b * N + (long)chunk * rows) * H2;
    float s = 0.f;
    for (int r = 0; r < rows; ++r) s += base[(long)r * H2 + c];
    atomicAdd(&meanbuf[b * H2 + c], s);
}

// ---------------- final FC ----------------
__global__ void fc_k(const float* __restrict__ meanbuf, const float* __restrict__ fcw,
                     const float* __restrict__ fcb, float* __restrict__ out, float invN) {
    int tid = threadIdx.x;   // 256
    int b = tid / TT, t = tid % TT;
    float s = 0.f;
    for (int c = 0; c < H2; ++c) s += meanbuf[b * H2 + c] * fcw[c * TT + t];
    out[tid] = s * invN + fcb[t];
}

extern "C" void kernel_launch(void* const* d_in, const int* in_sizes, int n_in,
                              void* d_out, int out_size, void* d_ws, size_t ws_size,
                              hipStream_t stream) {
    const float* x      = (const float*)d_in[0];
    const int*   nn     = (const int*)d_in[1];
    const float* theta0 = (const float*)d_in[2];
    const float* b0     = (const float*)d_in[3];
    const float* theta1 = (const float*)d_in[4];
    const float* b1     = (const float*)d_in[5];
    const float* fcw    = (const float*)d_in[6];
    const float* fcb    = (const float*)d_in[7];
    float* out = (float*)d_out;

    Perm perm;
    numpy_perm19(perm.p);

    const long M = (long)BB * NN;                 // 40000
    const int  E = BB * NN * KK;                  // 400000 entries
    const int  NB = (int)((M + 255) / 256);       // 157 scan blocks
    float* bufA = (float*)d_ws;                   // M*H1 floats
    float* bufB = bufA + M * H1;                  // M*H1 floats
    int*   dv      = (int*)(bufB + M * H1);       // M
    int*   offsets = dv + M;                      // M+1
    int*   cursor  = offsets + M + 1;             // M
    int*   entries = cursor + M;                  // E
    int*   bsum    = entries + E;                 // NB
    float* meanbuf = (float*)(bsum + NB);         // B*H2

    // --- inverse-CSR build (depends only on nn_idx) ---
    hipMemsetAsync(dv, 0, M * sizeof(int), stream);
    hipMemsetAsync(cursor, 0, M * sizeof(int), stream);
    count_dv<<<(int)((M + 255) / 256), 256, 0, stream>>>(nn, perm, dv, NN);
    block_sums<<<NB, 256, 0, stream>>>(dv, bsum, (int)M);
    scan_bsum<<<1, 256, 0, stream>>>(bsum, NB);
    write_offsets<<<NB, 256, 0, stream>>>(dv, bsum, offsets, (int)M);
    fill_entries<<<(E + 255) / 256, 256, 0, stream>>>(nn, perm, offsets, cursor, entries, NN);

    const int MB = (int)((M + 127) / 128);        // 313 row blocks

    // --- layer 1 ---
    gemm_mfma<<<dim3(H1 / 64, MB), 256, 0, stream>>>(x, theta0, bufA, (int)M, CIN, H1);
    edge_ef<H1><<<(int)M, H1, 0, stream>>>(bufA, nn, perm, bufB, NN);
    node_gather<H1><<<(int)M, H1, 0, stream>>>(bufB, offsets, entries, b0, bufA);
    // h1 in bufA [M, 256]

    // --- layer 2 ---
    gemm_mfma<<<dim3(H2 / 64, MB), 256, 0, stream>>>(bufA, theta1, bufB, (int)M, H1, H2);
    edge_ef<H2><<<(int)M, H2, 0, stream>>>(bufB, nn, perm, bufA, NN);
    node_gather<H2><<<(int)M, H2, 0, stream>>>(bufA, offsets, entries, b1, bufB);
    // h2 in bufB [M, 128]

    // --- mean over nodes + FC ---
    hipMemsetAsync(meanbuf, 0, BB * H2 * sizeof(float), stream);
    mean_partial<<<BB * 50, H2, 0, stream>>>(bufB, meanbuf, NN);
    fc_k<<<1, BB * TT, 0, stream>>>(meanbuf, fcw, fcb, out, 1.0f / (float)NN);
}

// Round 5
// 288.993 us; speedup vs baseline: 2.7499x; 1.2590x over previous
//
#include <hip/hip_runtime.h>
#include <hip/hip_bf16.h>

// Problem constants (from reference setup_inputs)
#define BB 4
#define NN 10000
#define CIN 512
#define H1 256
#define H2 128
#define TT 64
#define KK 10

struct Perm { int p[9]; };

// ---------------- host: exact numpy RandomState(0).permutation(19)[:9] ----------------
static void numpy_perm19(int* perm_out) {
    unsigned int mt[624];
    int mti;
    mt[0] = 0u;
    for (mti = 1; mti < 624; ++mti)
        mt[mti] = (unsigned int)(1812433253u * (mt[mti - 1] ^ (mt[mti - 1] >> 30)) + (unsigned int)mti);
    mti = 624;
    auto genrand = [&]() -> unsigned int {
        if (mti >= 624) {
            for (int kk = 0; kk < 624; ++kk) {
                unsigned int y = (mt[kk] & 0x80000000u) | (mt[(kk + 1) % 624] & 0x7fffffffu);
                mt[kk] = mt[(kk + 397) % 624] ^ (y >> 1) ^ ((y & 1u) ? 2567483615u : 0u);
            }
            mti = 0;
        }
        unsigned int y = mt[mti++];
        y ^= y >> 11;
        y ^= (y << 7) & 2636928640u;
        y ^= (y << 15) & 4022730752u;
        y ^= y >> 18;
        return y;
    };
    auto rk_interval = [&](unsigned int mx) -> unsigned int {
        if (mx == 0) return 0;
        unsigned int mask = mx;
        mask |= mask >> 1; mask |= mask >> 2; mask |= mask >> 4;
        mask |= mask >> 8; mask |= mask >> 16;
        unsigned int value;
        while ((value = (genrand() & mask)) > mx) {}
        return value;
    };
    int arr[19];
    for (int i = 0; i < 19; ++i) arr[i] = i;
    for (int i = 18; i >= 1; --i) {
        unsigned int j = rk_interval((unsigned int)i);
        int t = arr[j]; arr[j] = arr[i]; arr[i] = t;
    }
    for (int i = 0; i < 9; ++i) perm_out[i] = arr[i];
}

// ---------------- split-bf16 helpers ----------------
typedef __attribute__((ext_vector_type(8))) short bf16x8;
typedef __attribute__((ext_vector_type(4))) float f32x4;

__device__ __forceinline__ short f2bf(float f) {
    unsigned u = __float_as_uint(f);
    u = u + 0x7FFFu + ((u >> 16) & 1u);
    return (short)(u >> 16);
}
__device__ __forceinline__ float bf2f(short s) {
    return __uint_as_float(((unsigned)(unsigned short)s) << 16);
}
__device__ __forceinline__ float bf2f_u(unsigned short s) {
    return __uint_as_float(((unsigned)s) << 16);
}

// ---------------- split+transpose W: [K][N] f32 -> Th/Tl [N][K] bf16 ----------------
__global__ __launch_bounds__(256) void split_w(const float* __restrict__ W, short* __restrict__ Th,
                                               short* __restrict__ Tl, int K, int N) {
    __shared__ short sh[32][36], sl[32][36];   // [n][k], padded
    const int k0 = blockIdx.x * 32, n0 = blockIdx.y * 32;
    const int kr = threadIdx.x >> 3, c4 = (threadIdx.x & 7) * 4;
    float4 w = *(const float4*)&W[(long)(k0 + kr) * N + n0 + c4];
    float wv[4] = {w.x, w.y, w.z, w.w};
#pragma unroll
    for (int i = 0; i < 4; ++i) {
        short h = f2bf(wv[i]);
        sh[c4 + i][kr] = h;
        sl[c4 + i][kr] = f2bf(wv[i] - bf2f(h));
    }
    __syncthreads();
    const int nr = threadIdx.x >> 3;           // reuse mapping for write phase
    short4 h4, l4;
    h4.x = sh[nr][c4]; h4.y = sh[nr][c4 + 1]; h4.z = sh[nr][c4 + 2]; h4.w = sh[nr][c4 + 3];
    l4.x = sl[nr][c4]; l4.y = sl[nr][c4 + 1]; l4.z = sl[nr][c4 + 2]; l4.w = sl[nr][c4 + 3];
    *(short4*)&Th[(long)(n0 + nr) * K + k0 + c4] = h4;
    *(short4*)&Tl[(long)(n0 + nr) * K + k0 + c4] = l4;
}

// ---------------- GEMM1: Cb[M][256] bf16 = A[M][512] f32 @ Wt0 (split, 3-term) ----------------
// BM=64, BN=256 (full width), 4 waves x 64 cols, per-wave 4x4 16x16x32 frags.
__global__ __launch_bounds__(256) void gemm1(const float* __restrict__ A,
                                             const short* __restrict__ Bh,
                                             const short* __restrict__ Bl,
                                             unsigned short* __restrict__ Cb) {
    __shared__ short Ah[64][40], Al[64][40];   // 80B row stride (balanced banks)
    const int tid = threadIdx.x, lane = tid & 63, wid = tid >> 6;
    const int l15 = lane & 15, lq = lane >> 4;
    const long r0 = (long)blockIdx.x * 64;
    const int cbase = wid * 64;
    f32x4 acc[4][4] = {};
    const int row0 = tid >> 3, q0 = tid & 7;   // rows 0..31, float4 slot
    const int row1 = row0 + 32;
    float4 pre0 = *(const float4*)&A[(r0 + row0) * CIN + q0 * 4];
    float4 pre1 = *(const float4*)&A[(r0 + row1) * CIN + q0 * 4];
    for (int k0 = 0; k0 < CIN; k0 += 32) {
        {
            float v[8] = {pre0.x, pre0.y, pre0.z, pre0.w, pre1.x, pre1.y, pre1.z, pre1.w};
            short h[8], l[8];
#pragma unroll
            for (int i = 0; i < 8; ++i) { h[i] = f2bf(v[i]); l[i] = f2bf(v[i] - bf2f(h[i])); }
            *(short4*)&Ah[row0][q0 * 4] = make_short4(h[0], h[1], h[2], h[3]);
            *(short4*)&Al[row0][q0 * 4] = make_short4(l[0], l[1], l[2], l[3]);
            *(short4*)&Ah[row1][q0 * 4] = make_short4(h[4], h[5], h[6], h[7]);
            *(short4*)&Al[row1][q0 * 4] = make_short4(l[4], l[5], l[6], l[7]);
        }
        __syncthreads();
        if (k0 + 32 < CIN) {
            pre0 = *(const float4*)&A[(r0 + row0) * CIN + k0 + 32 + q0 * 4];
            pre1 = *(const float4*)&A[(r0 + row1) * CIN + k0 + 32 + q0 * 4];
        }
        bf16x8 bh[4], bl[4];
#pragma unroll
        for (int n = 0; n < 4; ++n) {
            long off = (long)(cbase + n * 16 + l15) * CIN + k0 + lq * 8;
            bh[n] = *(const bf16x8*)&Bh[off];
            bl[n] = *(const bf16x8*)&Bl[off];
        }
        bf16x8 afh[4], afl[4];
#pragma unroll
        for (int m = 0; m < 4; ++m) {
            int r = m * 16 + l15;
            afh[m] = *(const bf16x8*)&Ah[r][lq * 8];
            afl[m] = *(const bf16x8*)&Al[r][lq * 8];
        }
#pragma unroll
        for (int m = 0; m < 4; ++m)
#pragma unroll
            for (int n = 0; n < 4; ++n) {
                acc[m][n] = __builtin_amdgcn_mfma_f32_16x16x32_bf16(afh[m], bh[n], acc[m][n], 0, 0, 0);
                acc[m][n] = __builtin_amdgcn_mfma_f32_16x16x32_bf16(afl[m], bh[n], acc[m][n], 0, 0, 0);
                acc[m][n] = __builtin_amdgcn_mfma_f32_16x16x32_bf16(afh[m], bl[n], acc[m][n], 0, 0, 0);
            }
        __syncthreads();
    }
#pragma unroll
    for (int m = 0; m < 4; ++m)
#pragma unroll
        for (int n = 0; n < 4; ++n)
#pragma unroll
            for (int j = 0; j < 4; ++j) {
                long row = r0 + m * 16 + lq * 4 + j;
                int col = cbase + n * 16 + l15;
                Cb[row * H1 + col] = (unsigned short)f2bf(acc[m][n][j]);
            }
}

// ---------------- GEMM2: Cb[M][128] bf16 = A[M][256] bf16 @ Wt1 (split, 2-term) ----------------
__global__ __launch_bounds__(256) void gemm2(const unsigned short* __restrict__ A,
                                             const short* __restrict__ Bh,
                                             const short* __restrict__ Bl,
                                             unsigned short* __restrict__ Cb) {
    __shared__ short As[64][40];
    const int tid = threadIdx.x, lane = tid & 63, wid = tid >> 6;
    const int l15 = lane & 15, lq = lane >> 4;
    const long r0 = (long)blockIdx.x * 64;
    const int cbase = wid * 32;
    f32x4 acc[4][2] = {};
    const int srow = tid >> 2, sq = tid & 3;
    bf16x8 pre = *(const bf16x8*)&A[(r0 + srow) * H1 + sq * 8];
    for (int k0 = 0; k0 < H1; k0 += 32) {
        *(bf16x8*)&As[srow][sq * 8] = pre;
        __syncthreads();
        if (k0 + 32 < H1) pre = *(const bf16x8*)&A[(r0 + srow) * H1 + k0 + 32 + sq * 8];
        bf16x8 bh[2], bl[2];
#pragma unroll
        for (int n = 0; n < 2; ++n) {
            long off = (long)(cbase + n * 16 + l15) * H1 + k0 + lq * 8;
            bh[n] = *(const bf16x8*)&Bh[off];
            bl[n] = *(const bf16x8*)&Bl[off];
        }
        bf16x8 af[4];
#pragma unroll
        for (int m = 0; m < 4; ++m) af[m] = *(const bf16x8*)&As[m * 16 + l15][lq * 8];
#pragma unroll
        for (int m = 0; m < 4; ++m)
#pragma unroll
            for (int n = 0; n < 2; ++n) {
                acc[m][n] = __builtin_amdgcn_mfma_f32_16x16x32_bf16(af[m], bh[n], acc[m][n], 0, 0, 0);
                acc[m][n] = __builtin_amdgcn_mfma_f32_16x16x32_bf16(af[m], bl[n], acc[m][n], 0, 0, 0);
            }
        __syncthreads();
    }
#pragma unroll
    for (int m = 0; m < 4; ++m)
#pragma unroll
        for (int n = 0; n < 2; ++n)
#pragma unroll
            for (int j = 0; j < 4; ++j) {
                long row = r0 + m * 16 + lq * 4 + j;
                int col = cbase + n * 16 + l15;
                Cb[row * H2 + col] = (unsigned short)f2bf(acc[m][n][j]);
            }
}

// ---------------- dv counts ----------------
__global__ void count_dv(const int* __restrict__ nn, Perm perm, int* __restrict__ dv, int N) {
    int idx = blockIdx.x * blockDim.x + threadIdx.x;   // over B*N
    if (idx >= BB * N) return;
    int b = idx / N;
    atomicAdd(&dv[idx], 1);   // self
    const int* row = nn + (long)idx * (2 * KK - 1);
#pragma unroll
    for (int j = 0; j < KK - 1; ++j)
        atomicAdd(&dv[b * N + row[perm.p[j]]], 1);
}

// ---------------- multi-block exclusive scan: dv -> offsets ----------------
__global__ __launch_bounds__(256) void block_sums(const int* __restrict__ dv,
                                                  int* __restrict__ bsum, int M) {
    __shared__ int tmp[256];
    int i = blockIdx.x * 256 + threadIdx.x;
    tmp[threadIdx.x] = (i < M) ? dv[i] : 0;
    __syncthreads();
#pragma unroll
    for (int off = 128; off > 0; off >>= 1) {
        if (threadIdx.x < off) tmp[threadIdx.x] += tmp[threadIdx.x + off];
        __syncthreads();
    }
    if (threadIdx.x == 0) bsum[blockIdx.x] = tmp[0];
}

__global__ __launch_bounds__(256) void scan_bsum(int* __restrict__ bsum, int nb) {
    __shared__ int tmp[256];
    int v = (threadIdx.x < nb) ? bsum[threadIdx.x] : 0;
    tmp[threadIdx.x] = v;
    __syncthreads();
#pragma unroll
    for (int off = 1; off < 256; off <<= 1) {
        int t = (threadIdx.x >= off) ? tmp[threadIdx.x - off] : 0;
        __syncthreads();
        tmp[threadIdx.x] += t;
        __syncthreads();
    }
    if (threadIdx.x < nb) bsum[threadIdx.x] = tmp[threadIdx.x] - v;   // exclusive
}

__global__ __launch_bounds__(256) void write_offsets(const int* __restrict__ dv,
                                                     const int* __restrict__ bsum,
                                                     int* __restrict__ offsets, int M) {
    __shared__ int tmp[256];
    int i = blockIdx.x * 256 + threadIdx.x;
    int v = (i < M) ? dv[i] : 0;
    tmp[threadIdx.x] = v;
    __syncthreads();
#pragma unroll
    for (int off = 1; off < 256; off <<= 1) {
        int t = (threadIdx.x >= off) ? tmp[threadIdx.x - off] : 0;
        __syncthreads();
        tmp[threadIdx.x] += t;
        __syncthreads();
    }
    if (i < M) offsets[i] = bsum[blockIdx.x] + tmp[threadIdx.x] - v;
    if (i == M - 1) offsets[M] = bsum[blockIdx.x] + tmp[threadIdx.x];
}

// ---------------- fill inverse-CSR entries ----------------
__global__ void fill_entries(const int* __restrict__ nn, Perm perm,
                             const int* __restrict__ offsets, int* __restrict__ cursor,
                             int* __restrict__ entries, int N) {
    int j = blockIdx.x * blockDim.x + threadIdx.x;   // over B*N*K
    if (j >= BB * N * KK) return;
    int eg = j / KK, slot = j - eg * KK;
    int b = eg / N, e = eg - b * N;
    int node = (slot == 0) ? e : nn[(long)eg * (2 * KK - 1) + perm.p[slot - 1]];
    int g = b * N + node;
    int pos = atomicAdd(&cursor[g], 1);
    entries[offsets[g] + pos] = eg;
}

// ---------------- ef[e] = 0.1 * sum of 10 bf16 rows (H/2 threads, 4B loads) ----------------
template <int H>
__global__ void edge_ef_bf(const unsigned short* __restrict__ y, const int* __restrict__ nn,
                           Perm perm, unsigned short* __restrict__ ef, int N) {
    const int eg = blockIdx.x;            // b*N + e
    const int b = eg / N, e = eg - b * N;
    const int c = threadIdx.x;            // H/2 threads
    __shared__ int idx[KK];
    if (threadIdx.x < KK)
        idx[threadIdx.x] = (threadIdx.x == 0) ? e : nn[(long)eg * (2 * KK - 1) + perm.p[threadIdx.x - 1]];
    __syncthreads();
    const unsigned short* yb = y + (long)b * N * H;
    float s0 = 0.f, s1 = 0.f;
#pragma unroll
    for (int i = 0; i < KK; ++i) {
        unsigned v = *(const unsigned*)&yb[(long)idx[i] * H + c * 2];
        s0 += bf2f_u((unsigned short)(v & 0xFFFFu));
        s1 += bf2f_u((unsigned short)(v >> 16));
    }
    unsigned o = (((unsigned)(unsigned short)f2bf(0.1f * s1)) << 16) |
                 (unsigned)(unsigned short)f2bf(0.1f * s0);
    *(unsigned*)&ef[(long)eg * H + c * 2] = o;
}

// ---------------- out[v] = (sum ef over edge list)/dv + bias, leaky_relu -> bf16 ----------------
template <int H>
__global__ void node_gather_bf(const unsigned short* __restrict__ ef, const int* __restrict__ offsets,
                               const int* __restrict__ entries, const float* __restrict__ bias,
                               unsigned short* __restrict__ out) {
    const int g = blockIdx.x;             // b*N + v
    const int c = threadIdx.x;            // H/2 threads
    const int s0o = offsets[g], s1o = offsets[g + 1];
    const int cnt = s1o - s0o;            // == dv[g], >= 1
    __shared__ int eidx[64];
    float a0 = 0.f, a1 = 0.f;
    for (int base = s0o; base < s1o; base += 64) {
        int m = min(64, s1o - base);
        if (threadIdx.x < m) eidx[threadIdx.x] = entries[base + threadIdx.x];
        __syncthreads();
        for (int i = 0; i < m; ++i) {
            unsigned v = *(const unsigned*)&ef[(long)eidx[i] * H + c * 2];
            a0 += bf2f_u((unsigned short)(v & 0xFFFFu));
            a1 += bf2f_u((unsigned short)(v >> 16));
        }
        __syncthreads();
    }
    float inv = 1.f / (float)cnt;
    float v0 = a0 * inv + bias[c * 2];
    float v1 = a1 * inv + bias[c * 2 + 1];
    v0 = v0 >= 0.f ? v0 : 0.01f * v0;
    v1 = v1 >= 0.f ? v1 : 0.01f * v1;
    unsigned o = (((unsigned)(unsigned short)f2bf(v1)) << 16) | (unsigned)(unsigned short)f2bf(v0);
    *(unsigned*)&out[(long)g * H + c * 2] = o;
}

// ---------------- mean over nodes (bf16 input, partial sums + atomics) ----------------
__global__ void mean_partial(const unsigned short* __restrict__ h2, float* __restrict__ meanbuf, int N) {
    const int CH = 50;
    int b = blockIdx.x / CH;
    int chunk = blockIdx.x % CH;
    int c = threadIdx.x;                  // 64 threads, 2 ch each
    int rows = N / CH;
    const unsigned short* base = h2 + ((long)b * N + (long)chunk * rows) * H2;
    float s0 = 0.f, s1 = 0.f;
    for (int r = 0; r < rows; ++r) {
        unsigned v = *(const unsigned*)&base[(long)r * H2 + c * 2];
        s0 += bf2f_u((unsigned short)(v & 0xFFFFu));
        s1 += bf2f_u((unsigned short)(v >> 16));
    }
    atomicAdd(&meanbuf[b * H2 + c * 2], s0);
    atomicAdd(&meanbuf[b * H2 + c * 2 + 1], s1);
}

// ---------------- final FC ----------------
__global__ void fc_k(const float* __restrict__ meanbuf, const float* __restrict__ fcw,
                     const float* __restrict__ fcb, float* __restrict__ out, float invN) {
    int tid = threadIdx.x;   // 256
    int b = tid / TT, t = tid % TT;
    float s = 0.f;
    for (int c = 0; c < H2; ++c) s += meanbuf[b * H2 + c] * fcw[c * TT + t];
    out[tid] = s * invN + fcb[t];
}

extern "C" void kernel_launch(void* const* d_in, const int* in_sizes, int n_in,
                              void* d_out, int out_size, void* d_ws, size_t ws_size,
                              hipStream_t stream) {
    const float* x      = (const float*)d_in[0];
    const int*   nn     = (const int*)d_in[1];
    const float* theta0 = (const float*)d_in[2];
    const float* b0     = (const float*)d_in[3];
    const float* theta1 = (const float*)d_in[4];
    const float* b1     = (const float*)d_in[5];
    const float* fcw    = (const float*)d_in[6];
    const float* fcb    = (const float*)d_in[7];
    float* out = (float*)d_out;

    Perm perm;
    numpy_perm19(perm.p);

    const long M = (long)BB * NN;                 // 40000
    const int  E = BB * NN * KK;                  // 400000 entries
    const int  NB = (int)((M + 255) / 256);       // 157 scan blocks

    unsigned short* bufY = (unsigned short*)d_ws;         // M*H1 bf16 (y / y1)
    unsigned short* bufE = bufY + M * H1;                 // M*H1 bf16 (ef)
    unsigned short* bufH = bufE + M * H1;                 // M*H1 bf16 (h1 / h2)
    short* W0h = (short*)(bufH + M * H1);                 // H1*CIN
    short* W0l = W0h + (long)H1 * CIN;
    short* W1h = W0l + (long)H1 * CIN;                    // H2*H1
    short* W1l = W1h + (long)H2 * H1;
    int*   dv      = (int*)(W1l + (long)H2 * H1);         // M
    int*   offsets = dv + M;                              // M+1
    int*   cursor  = offsets + M + 1;                     // M
    int*   entries = cursor + M;                          // E
    int*   bsum    = entries + E;                         // NB
    float* meanbuf = (float*)(bsum + NB);                 // B*H2

    // --- inverse-CSR build (depends only on nn_idx) ---
    hipMemsetAsync(dv, 0, M * sizeof(int), stream);
    hipMemsetAsync(cursor, 0, M * sizeof(int), stream);
    count_dv<<<(int)((M + 255) / 256), 256, 0, stream>>>(nn, perm, dv, NN);
    block_sums<<<NB, 256, 0, stream>>>(dv, bsum, (int)M);
    scan_bsum<<<1, 256, 0, stream>>>(bsum, NB);
    write_offsets<<<NB, 256, 0, stream>>>(dv, bsum, offsets, (int)M);
    fill_entries<<<(E + 255) / 256, 256, 0, stream>>>(nn, perm, offsets, cursor, entries, NN);

    // --- pre-split weights (transposed hi/lo bf16) ---
    split_w<<<dim3(CIN / 32, H1 / 32), 256, 0, stream>>>(theta0, W0h, W0l, CIN, H1);
    split_w<<<dim3(H1 / 32, H2 / 32), 256, 0, stream>>>(theta1, W1h, W1l, H1, H2);

    const int GB = (int)(M / 64);                 // 625 row blocks

    // --- layer 1 ---
    gemm1<<<GB, 256, 0, stream>>>(x, W0h, W0l, bufY);
    edge_ef_bf<H1><<<(int)M, H1 / 2, 0, stream>>>(bufY, nn, perm, bufE, NN);
    node_gather_bf<H1><<<(int)M, H1 / 2, 0, stream>>>(bufE, offsets, entries, b0, bufH);
    // h1 in bufH [M][256] bf16

    // --- layer 2 ---
    gemm2<<<GB, 256, 0, stream>>>(bufH, W1h, W1l, bufY);
    edge_ef_bf<H2><<<(int)M, H2 / 2, 0, stream>>>(bufY, nn, perm, bufE, NN);
    node_gather_bf<H2><<<(int)M, H2 / 2, 0, stream>>>(bufE, offsets, entries, b1, bufH);
    // h2 in bufH [M][128] bf16

    // --- mean over nodes + FC ---
    hipMemsetAsync(meanbuf, 0, BB * H2 * sizeof(float), stream);
    mean_partial<<<BB * 50, H2 / 2, 0, stream>>>(bufH, meanbuf, NN);
    fc_k<<<1, BB * TT, 0, stream>>>(meanbuf, fcw, fcb, out, 1.0f / (float)NN);
}